// Round 19
// baseline (241.519 us; speedup 1.0000x reference)
//
#include <hip/hip_runtime.h>
#include <math.h>

// Problem constants (B=2, L=2048, D=1024, H=16, FACTOR=5)
#define B_ 2
#define L_ 2048
#define D_ 1024
#define H_ 16
#define DH_ 64
#define U_ 40
#define SCALE_ 0.125f

typedef __attribute__((ext_vector_type(8))) short short8v;            // 8 bf16
typedef __attribute__((ext_vector_type(4))) float f32x4;
typedef __attribute__((ext_vector_type(4))) unsigned short ushort4v;  // 8 B

static __device__ __forceinline__ unsigned short bf16_rne(float f) {
  unsigned int u = __float_as_uint(f);
  u += 0x7fff + ((u >> 16) & 1);
  return (unsigned short)(u >> 16);
}
static __device__ __forceinline__ float bf16_f32(unsigned short h) {
  return __uint_as_float(((unsigned int)h) << 16);
}

// Async global->LDS, 16 B per lane.
static __device__ __forceinline__ void gload16(const unsigned short* src,
                                               unsigned short* lds) {
  __builtin_amdgcn_global_load_lds(
      (const __attribute__((address_space(1))) void*)src,
      (__attribute__((address_space(3))) void*)lds, 16, 0, 0);
}

#define BARRIER                                  \
  do {                                           \
    asm volatile("" ::: "memory");               \
    __builtin_amdgcn_s_barrier();                \
    asm volatile("" ::: "memory");               \
  } while (0)
// Rule #18: force all LDS reads to retire and pin instruction movement.
#define LGKM0                                          \
  do {                                                 \
    asm volatile("s_waitcnt lgkmcnt(0)" ::: "memory"); \
    __builtin_amdgcn_sched_barrier(0);                 \
  } while (0)

// ---------------------------------------------------------------------------
// Pre-split f32 -> (hi,lo) bf16 for W=[Wq;Wkv] (quads [0,nW)) and X (rest).
// Block 0 additionally zeroes the vmean accumulator (in d_out[0:2048]).
// ---------------------------------------------------------------------------
__global__ __launch_bounds__(256) void split_all(
    const float* __restrict__ Wq, const float* __restrict__ Wkv,
    const float* __restrict__ X, unsigned short* __restrict__ Whi,
    unsigned short* __restrict__ Wlo, unsigned short* __restrict__ Xhi,
    unsigned short* __restrict__ Xlo, float* __restrict__ vmAcc, int nW) {
  if (blockIdx.x == 0) {
    for (int z = threadIdx.x; z < B_ * D_; z += 256) vmAcc[z] = 0.f;
  }
  int i = blockIdx.x * 256 + threadIdx.x;
  const int nq_q = (D_ * D_) / 4;
  float4 v;
  unsigned short *hi, *lo;
  int off;
  if (i < nW) {
    v = (i < nq_q) ? ((const float4*)Wq)[i] : ((const float4*)Wkv)[i - nq_q];
    hi = Whi; lo = Wlo; off = i;
  } else {
    off = i - nW;
    v = ((const float4*)X)[off];
    hi = Xhi; lo = Xlo;
  }
  float vv[4] = {v.x, v.y, v.z, v.w};
  ushort4v h, l;
#pragma unroll
  for (int e = 0; e < 4; ++e) {
    unsigned short hh = bf16_rne(vv[e]);
    h[e] = hh;
    l[e] = bf16_rne(vv[e] - bf16_f32(hh));
  }
  ((ushort4v*)hi)[off] = h;
  ((ushort4v*)lo)[off] = l;
}

// ---------------------------------------------------------------------------
// Pipelined split-bf16 MFMA GEMM: 256x192 tile, 16 waves, 2 LDS buffers,
// 1 barrier/step. R19: blockIdx.x = ROW tile so all 16 col-blocks sharing
// an A panel land on the same XCD (bid&7 = x&7) -> A (16 MB, the larger
// operand) becomes L2-local instead of 8x cross-XCD re-fetch.
// ---------------------------------------------------------------------------
__global__ __launch_bounds__(1024, 1) void gemm_qkv_16w(
    const unsigned short* __restrict__ Xhi,
    const unsigned short* __restrict__ Xlo,
    const unsigned short* __restrict__ Whi,
    const unsigned short* __restrict__ Wlo,
    const float* __restrict__ bq, const float* __restrict__ bkv,
    float* __restrict__ Qo, float* __restrict__ Ko, float* __restrict__ Vo,
    float* __restrict__ vmAcc) {
  __shared__ unsigned short LDS[2][28672];
  const int tid = threadIdx.x;
  const int lane = tid & 63;
  const int wave = tid >> 6;
  const int wm = wave >> 2, wn = wave & 3;
  const int row0 = blockIdx.x * 256;    // M = 4096 -> 16 row tiles (XCD key)
  const int col0 = blockIdx.y * 192;    // N = 3072 -> 16 col tiles

  f32x4 acc[4][3] = {};

  const unsigned short* gsrc[4];
  int gcv[4];
#pragma unroll
  for (int r = 0; r < 4; ++r) {
    int c = (r < 3) ? (wave + 16 * r) : (48 + (wave & 7));
    gcv[r] = c;
    const unsigned short* base;
    int rowin, isA;
    if (c < 16)      { base = Xhi; rowin = c * 16;        isA = 1; }
    else if (c < 32) { base = Xlo; rowin = (c - 16) * 16; isA = 1; }
    else if (c < 44) { base = Whi; rowin = (c - 32) * 16; isA = 0; }
    else             { base = Wlo; rowin = (c - 44) * 16; isA = 0; }
    rowin += (lane >> 2);
    int grow = (isA ? row0 : col0) + rowin;
    int seg = (lane & 3) ^ ((rowin >> 1) & 3);
    gsrc[r] = base + (size_t)grow * D_ + seg * 8;
  }

  const int fr_r = lane & 15;
  const int hs = lane >> 4;

#define STG_ALL(k0s, Ls)                                        \
  do {                                                          \
    gload16(gsrc[0] + (k0s), (Ls) + gcv[0] * 512);              \
    gload16(gsrc[1] + (k0s), (Ls) + gcv[1] * 512);              \
    gload16(gsrc[2] + (k0s), (Ls) + gcv[2] * 512);              \
    if (wave < 8) gload16(gsrc[3] + (k0s), (Ls) + gcv[3] * 512);\
  } while (0)

  STG_ALL(0, &LDS[0][0]);
  asm volatile("s_waitcnt vmcnt(0)" ::: "memory");
  BARRIER;

  for (int ks = 0; ks < 32; ++ks) {
    unsigned short* Lc = &LDS[ks & 1][0];
    unsigned short* Ls = &LDS[(ks + 1) & 1][0];
    if (ks < 31) STG_ALL((ks + 1) * 32, Ls);

    short8v a_h[4], a_l[4], b_h[3], b_l[3];
#pragma unroll
    for (int ni = 0; ni < 3; ++ni) {
      int rc = wn * 48 + ni * 16 + fr_r;
      int off = rc * 32 + ((hs ^ ((rc >> 1) & 3)) << 3);
      b_h[ni] = *(const short8v*)&Lc[16384 + off];
      b_l[ni] = *(const short8v*)&Lc[22528 + off];
    }
#pragma unroll
    for (int mi = 0; mi < 4; ++mi) {
      int rr = wm * 64 + mi * 16 + fr_r;
      int off = rr * 32 + ((hs ^ ((rr >> 1) & 3)) << 3);
      a_h[mi] = *(const short8v*)&Lc[off];
      a_l[mi] = *(const short8v*)&Lc[8192 + off];
    }

#pragma unroll
    for (int mi = 0; mi < 4; ++mi)
#pragma unroll
      for (int ni = 0; ni < 3; ++ni) {
        acc[mi][ni] = __builtin_amdgcn_mfma_f32_16x16x32_bf16(
            a_h[mi], b_h[ni], acc[mi][ni], 0, 0, 0);
        acc[mi][ni] = __builtin_amdgcn_mfma_f32_16x16x32_bf16(
            a_h[mi], b_l[ni], acc[mi][ni], 0, 0, 0);
        acc[mi][ni] = __builtin_amdgcn_mfma_f32_16x16x32_bf16(
            a_l[mi], b_h[ni], acc[mi][ni], 0, 0, 0);
      }

    LGKM0;
    asm volatile("s_waitcnt vmcnt(0)" ::: "memory");
    BARRIER;
  }

  // Epilogue: C/D layout col=lane&15, row=(lane>>4)*4+reg.
#pragma unroll
  for (int ni = 0; ni < 3; ++ni) {
    int c = col0 + wn * 48 + ni * 16 + (lane & 15);
    int which = c >> 10;
    int jj = c & (D_ - 1);
    int h = jj >> 6, dh = jj & 63;
    float bias = (c < D_) ? bq[c] : bkv[c - D_];
    float* dst = (which == 0) ? Qo : ((which == 1) ? Ko : Vo);
#pragma unroll
    for (int mi = 0; mi < 4; ++mi) {
#pragma unroll
      for (int reg = 0; reg < 4; ++reg) {
        int r = row0 + wm * 64 + mi * 16 + ((lane >> 4) << 2) + reg;
        int b = r >> 11, l = r & (L_ - 1);
        dst[(((size_t)b * H_ + h) * L_ + l) * DH_ + dh] =
            acc[mi][ni][reg] + bias;
      }
    }
    if (which == 2) {  // vmean partial: sum over this wave's 64 rows
      float s = 0.f;
#pragma unroll
      for (int mi = 0; mi < 4; ++mi)
#pragma unroll
        for (int reg = 0; reg < 4; ++reg) s += acc[mi][ni][reg];
      s += __shfl_xor(s, 16);
      s += __shfl_xor(s, 32);
      if ((lane >> 4) == 0)
        atomicAdd(&vmAcc[(row0 >> 11) * D_ + jj], s + 64.0f * bias);
    }
  }
#undef STG_ALL
}

// ---------------------------------------------------------------------------
// Fallback GEMM (R10 structure) — used only when ws can't hold Xhi/Xlo.
// ---------------------------------------------------------------------------
__global__ __launch_bounds__(256) void gemm_qkv_fallback(
    const float* __restrict__ X,
    const unsigned short* __restrict__ Whi,
    const unsigned short* __restrict__ Wlo,
    const float* __restrict__ bq, const float* __restrict__ bkv,
    float* __restrict__ Qo, float* __restrict__ Ko, float* __restrict__ Vo,
    float* __restrict__ vmAcc) {
  __shared__ unsigned short Ah[128 * 32];
  __shared__ unsigned short Al[128 * 32];
  __shared__ unsigned short Bh[128 * 32];
  __shared__ unsigned short Bl[128 * 32];
  const int tid = threadIdx.x;
  const int lane = tid & 63;
  const int wave = tid >> 6;
  const int wm = wave >> 1, wn = wave & 1;
  const int row0 = blockIdx.y * 128;
  const int col0 = blockIdx.x * 128;

  f32x4 acc[4][4] = {};

  const int grow = lane >> 2;
  const int gg = lane & 3;

  for (int k0 = 0; k0 < D_; k0 += 32) {
#pragma unroll
    for (int j = 0; j < 2; ++j) {
      int c = wave + 4 * j;
      int row = c * 16 + grow;
      int gsrc = (gg ^ ((row >> 1) & 3)) << 3;
      size_t soffB = (size_t)(col0 + row) * D_ + k0 + gsrc;
      gload16(Whi + soffB, Bh + c * 512);
      gload16(Wlo + soffB, Bl + c * 512);
    }
#pragma unroll
    for (int rep = 0; rep < 2; ++rep) {
      int task = tid + rep * 256;
      int row = task >> 2;
      int gt = task & 3;
      const float* s = X + (size_t)(row0 + row) * D_ + k0 + gt * 8;
      float4 a0 = *(const float4*)s;
      float4 a1 = *(const float4*)(s + 4);
      float av[8] = {a0.x, a0.y, a0.z, a0.w, a1.x, a1.y, a1.z, a1.w};
      short8v hseg, lseg;
#pragma unroll
      for (int e = 0; e < 8; ++e) {
        unsigned short hh = bf16_rne(av[e]);
        hseg[e] = (short)hh;
        lseg[e] = (short)bf16_rne(av[e] - bf16_f32(hh));
      }
      int dst = row * 32 + ((gt ^ ((row >> 1) & 3)) << 3);
      *(short8v*)&Ah[dst] = hseg;
      *(short8v*)&Al[dst] = lseg;
    }
    __syncthreads();

    short8v a_h[4], a_l[4], b_h[4], b_l[4];
    const int hs = lane >> 4;
#pragma unroll
    for (int mi = 0; mi < 4; ++mi) {
      int rr = wm * 64 + mi * 16 + (lane & 15);
      int off = rr * 32 + ((hs ^ ((rr >> 1) & 3)) << 3);
      a_h[mi] = *(const short8v*)&Ah[off];
      a_l[mi] = *(const short8v*)&Al[off];
    }
#pragma unroll
    for (int ni = 0; ni < 4; ++ni) {
      int rc = wn * 64 + ni * 16 + (lane & 15);
      int off = rc * 32 + ((hs ^ ((rc >> 1) & 3)) << 3);
      b_h[ni] = *(const short8v*)&Bh[off];
      b_l[ni] = *(const short8v*)&Bl[off];
    }
#pragma unroll
    for (int mi = 0; mi < 4; ++mi)
#pragma unroll
      for (int ni = 0; ni < 4; ++ni) {
        acc[mi][ni] = __builtin_amdgcn_mfma_f32_16x16x32_bf16(
            a_h[mi], b_h[ni], acc[mi][ni], 0, 0, 0);
        acc[mi][ni] = __builtin_amdgcn_mfma_f32_16x16x32_bf16(
            a_h[mi], b_l[ni], acc[mi][ni], 0, 0, 0);
        acc[mi][ni] = __builtin_amdgcn_mfma_f32_16x16x32_bf16(
            a_l[mi], b_h[ni], acc[mi][ni], 0, 0, 0);
      }
    __syncthreads();
  }

#pragma unroll
  for (int ni = 0; ni < 4; ++ni) {
    int c = col0 + wn * 64 + ni * 16 + (lane & 15);
    int which = c >> 10;
    int jj = c & (D_ - 1);
    int h = jj >> 6, dh = jj & 63;
    float bias = (c < D_) ? bq[c] : bkv[c - D_];
    float* dst = (which == 0) ? Qo : ((which == 1) ? Ko : Vo);
#pragma unroll
    for (int mi = 0; mi < 4; ++mi) {
#pragma unroll
      for (int reg = 0; reg < 4; ++reg) {
        int r = row0 + wm * 64 + mi * 16 + ((lane >> 4) << 2) + reg;
        int b = r >> 11, l = r & (L_ - 1);
        dst[(((size_t)b * H_ + h) * L_ + l) * DH_ + dh] =
            acc[mi][ni][reg] + bias;
      }
    }
    if (which == 2) {
      float s = 0.f;
#pragma unroll
      for (int mi = 0; mi < 4; ++mi)
#pragma unroll
        for (int reg = 0; reg < 4; ++reg) s += acc[mi][ni][reg];
      s += __shfl_xor(s, 16);
      s += __shfl_xor(s, 32);
      if ((lane >> 4) == 0)
        atomicAdd(&vmAcc[(row0 >> 11) * D_ + jj], s + 64.0f * bias);
    }
  }
}

// ---------------------------------------------------------------------------
// Merged kernel A: blocks [0,4096) = sample_m; blocks [4096,4128) = base.
// sample_m: bh = bid&31 -> all 128 blocks of one bh share an XCD.
// ---------------------------------------------------------------------------
__global__ __launch_bounds__(256) void sample_base(
    const float* __restrict__ Q, const float* __restrict__ Kt,
    const int* __restrict__ idx, float* __restrict__ Mv,
    const float* __restrict__ vmAcc, const float* __restrict__ Wout,
    const float* __restrict__ bout, float* __restrict__ baseOut,
    float* __restrict__ vmeanM) {
  int t = threadIdx.x;
  if (blockIdx.x < 4096) {
    int bh = blockIdx.x & 31;
    int chunk = blockIdx.x >> 5;
    int w = t >> 6, lane = t & 63;
    int subl = lane >> 4, d16 = lane & 15;
    int l = chunk * 16 + w * 4 + subl;
    int gl = bh * L_ + l;
    const float4* Kb4 = (const float4*)(Kt + (size_t)bh * L_ * DH_);
    float4 q4 = ((const float4*)(Q + (size_t)gl * DH_))[d16];
    const int* irow = idx + l * U_;
    float mx = -INFINITY, sm = 0.f;
#pragma unroll 8
    for (int u = 0; u < U_; ++u) {
      int kl = irow[u];
      float4 k4 = Kb4[kl * 16 + d16];
      float p = q4.x * k4.x + q4.y * k4.y + q4.z * k4.z + q4.w * k4.w;
      p += __shfl_xor(p, 1);
      p += __shfl_xor(p, 2);
      p += __shfl_xor(p, 4);
      p += __shfl_xor(p, 8);
      mx = fmaxf(mx, p);
      sm += p;
    }
    if (d16 == 0) Mv[gl] = mx - sm * (1.0f / U_);
  } else {
    int bid = blockIdx.x - 4096;
    int b = bid >> 4, jc = bid & 15;
    int j = jc * 64 + (t & 63);
    int isl = t >> 6;
    __shared__ float vm[D_];
    __shared__ float red[256];
    for (int i = t; i < D_; i += 256) vm[i] = vmAcc[b * D_ + i] * (1.0f / L_);
    __syncthreads();
    if (jc == 0)
      for (int i = t; i < D_; i += 256) vmeanM[b * D_ + i] = vm[i];
    float s = 0.f;
    const float* wr = Wout + (size_t)j * D_ + isl * 256;
    const float* vv = vm + isl * 256;
    for (int i = 0; i < 256; i += 4) {
      float4 w = *(const float4*)(wr + i);
      s += vv[i] * w.x + vv[i + 1] * w.y + vv[i + 2] * w.z + vv[i + 3] * w.w;
    }
    red[t] = s;
    __syncthreads();
    if (isl == 0)
      baseOut[b * D_ + j] =
          red[t] + red[t + 64] + red[t + 128] + red[t + 192] + bout[j];
  }
}

// ---------------------------------------------------------------------------
// Merged kernel B: blocks [0,4096) = bcast_out; [4096,4128) = topk.
// ---------------------------------------------------------------------------
__global__ __launch_bounds__(256) void bcast_topk(
    const float* __restrict__ baseIn, float* __restrict__ out,
    const float* __restrict__ Mv, int* __restrict__ topIdx) {
  int t = threadIdx.x;
  if (blockIdx.x < 4096) {
    size_t i4 = (size_t)blockIdx.x * 256 + t;
    size_t i = i4 * 4;
    int b = (int)(i >> 21);
    int col = (int)(i & (D_ - 1));
    *(float4*)(out + i) = *(const float4*)(baseIn + b * D_ + col);
  } else {
    __shared__ float vals[L_];
    int lane = t & 63;
    int bh = blockIdx.x - 4096;
    for (int j = t; j < L_; j += 256) vals[j] = Mv[(size_t)bh * L_ + j];
    __syncthreads();
    for (int it = 0; it < U_; ++it) {
      float bv = -INFINITY;
      int bi = 0x7fffffff;
      for (int j = 0; j < 32; ++j) {
        int i = j * 64 + lane;
        float v = vals[i];
        if (v > bv) { bv = v; bi = i; }
      }
#pragma unroll
      for (int off = 32; off > 0; off >>= 1) {
        float ov = __shfl_xor(bv, off);
        int oi = __shfl_xor(bi, off);
        if (ov > bv || (ov == bv && oi < bi)) { bv = ov; bi = oi; }
      }
      if (t == 0) topIdx[bh * U_ + it] = bi;
      vals[bi] = -INFINITY;  // all waves compute identical bi
      __syncthreads();
    }
  }
}

// ---------------------------------------------------------------------------
// Fused attention + output correction. Grid (32, 8): blockIdx.x = bh so the
// 8 qc-blocks of one bh share an XCD (K+V fetched once per XCD).
// ---------------------------------------------------------------------------
__global__ __launch_bounds__(256) void attn_corr(
    const float* __restrict__ Q, const float* __restrict__ Kt,
    const float* __restrict__ Vt, const int* __restrict__ topIdx,
    const float* __restrict__ vmeanM, const float* __restrict__ Wout,
    float* __restrict__ out) {
  int bh = blockIdx.x;  // 0..31
  int qc = blockIdx.y;  // 0..7 (5 queries each)
  int b = bh >> 4, h = bh & (H_ - 1);
  __shared__ float Qs[5][DH_];
  __shared__ float Sv[5][L_];
  __shared__ float part[4][5][DH_];
  __shared__ float inv[5];
  __shared__ float dv[5][DH_];
  __shared__ int lq[5];
  int t = threadIdx.x;
  int lane = t & 63, w = t >> 6;

  if (t < 80) {
    int q = t >> 4, c4 = t & 15;
    int ql = topIdx[bh * U_ + qc * 5 + q];
    *(float4*)&Qs[q][c4 * 4] =
        *(const float4*)&Q[((size_t)bh * L_ + ql) * DH_ + c4 * 4];
  }
  if (t < 5) lq[t] = topIdx[bh * U_ + qc * 5 + t];
  __syncthreads();

  const float* Kb = Kt + (size_t)bh * L_ * DH_;
  for (int kc = 0; kc < 8; ++kc) {
    int key = kc * 256 + t;
    const float* kr = Kb + (size_t)key * DH_;
    float acc[5];
#pragma unroll
    for (int q = 0; q < 5; ++q) acc[q] = 0.f;
#pragma unroll
    for (int i4 = 0; i4 < 16; ++i4) {
      float4 k4 = *(const float4*)(kr + i4 * 4);
#pragma unroll
      for (int q = 0; q < 5; ++q) {
        float4 qv = *(const float4*)&Qs[q][i4 * 4];
        acc[q] += k4.x * qv.x + k4.y * qv.y + k4.z * qv.z + k4.w * qv.w;
      }
    }
#pragma unroll
    for (int q = 0; q < 5; ++q) Sv[q][key] = acc[q] * SCALE_;
  }
  __syncthreads();

#pragma unroll
  for (int rep = 0; rep < 2; ++rep) {
    int r = (rep == 0) ? w : (w == 0 ? 4 : -1);
    if (r >= 0) {
      float mx = -INFINITY;
      for (int j = 0; j < 32; ++j) mx = fmaxf(mx, Sv[r][j * 64 + lane]);
#pragma unroll
      for (int off = 1; off < 64; off <<= 1)
        mx = fmaxf(mx, __shfl_xor(mx, off));
      float sm = 0.f;
      for (int j = 0; j < 32; ++j) {
        float e = __expf(Sv[r][j * 64 + lane] - mx);
        Sv[r][j * 64 + lane] = e;
        sm += e;
      }
#pragma unroll
      for (int off = 1; off < 64; off <<= 1) sm += __shfl_xor(sm, off);
      if (lane == 0) inv[r] = 1.0f / sm;
    }
  }
  __syncthreads();

  {
    const float* vb = Vt + ((size_t)bh * L_ + w * 512) * DH_ + lane;
    float acc[5];
#pragma unroll
    for (int q = 0; q < 5; ++q) acc[q] = 0.f;
#pragma unroll 8
    for (int k4 = 0; k4 < 128; ++k4) {
      float v0 = vb[(k4 * 4 + 0) * DH_];
      float v1 = vb[(k4 * 4 + 1) * DH_];
      float v2 = vb[(k4 * 4 + 2) * DH_];
      float v3 = vb[(k4 * 4 + 3) * DH_];
      int k = w * 512 + k4 * 4;
#pragma unroll
      for (int q = 0; q < 5; ++q) {
        float4 p4 = *(const float4*)&Sv[q][k];
        acc[q] += p4.x * v0 + p4.y * v1 + p4.z * v2 + p4.w * v3;
      }
    }
#pragma unroll
    for (int q = 0; q < 5; ++q) part[w][q][lane] = acc[q];
  }
  __syncthreads();

  for (int o = t; o < 5 * DH_; o += 256) {
    int q = o >> 6, dh = o & 63;
    float s = (part[0][q][dh] + part[1][q][dh]) +
              (part[2][q][dh] + part[3][q][dh]);
    dv[q][dh] = s * inv[q] - vmeanM[b * D_ + h * DH_ + dh];
  }
  __syncthreads();

  int sub = t & 3;
  int jbase = t >> 2;
#pragma unroll
  for (int jc = 0; jc < 16; ++jc) {
    int j = jc * 64 + jbase;
    const float* wr = Wout + (size_t)j * D_ + h * DH_ + sub * 16;
    float4 w0 = ((const float4*)wr)[0];
    float4 w1 = ((const float4*)wr)[1];
    float4 w2 = ((const float4*)wr)[2];
    float4 w3 = ((const float4*)wr)[3];
#pragma unroll
    for (int q = 0; q < 5; ++q) {
      const float* dq = &dv[q][sub * 16];
      float s = dq[0] * w0.x + dq[1] * w0.y + dq[2] * w0.z + dq[3] * w0.w +
                dq[4] * w1.x + dq[5] * w1.y + dq[6] * w1.z + dq[7] * w1.w +
                dq[8] * w2.x + dq[9] * w2.y + dq[10] * w2.z + dq[11] * w2.w +
                dq[12] * w3.x + dq[13] * w3.y + dq[14] * w3.z + dq[15] * w3.w;
      s += __shfl_xor(s, 1);
      s += __shfl_xor(s, 2);
      if (sub == 0)
        atomicAdd(out + ((size_t)b * L_ + lq[q]) * D_ + j, s);
    }
  }
}

// ---------------------------------------------------------------------------
extern "C" void kernel_launch(void* const* d_in, const int* in_sizes, int n_in,
                              void* d_out, int out_size, void* d_ws,
                              size_t ws_size, hipStream_t stream) {
  const float* x    = (const float*)d_in[0];
  const float* Wq   = (const float*)d_in[1];
  const float* bq   = (const float*)d_in[2];
  const float* Wkv  = (const float*)d_in[3];
  const float* bkv  = (const float*)d_in[4];
  const float* Wout = (const float*)d_in[5];
  const float* bout = (const float*)d_in[6];
  const int*   idx  = (const int*)d_in[7];
  float* out = (float*)d_out;

  float* ws = (float*)d_ws;
  const size_t NQ = (size_t)B_ * H_ * L_ * DH_;  // 4,194,304 floats
  float* Q  = ws;
  float* Kt = Q + NQ;
  float* Vt = Kt + NQ;
  // W/X split region (live only through the GEMM)
  unsigned short* Whi = (unsigned short*)(Vt + NQ);  // 6 MB
  unsigned short* Wlo = Whi + (size_t)3 * D_ * D_;   // 6 MB
  unsigned short* Xhi = Wlo + (size_t)3 * D_ * D_;   // 8 MB (optional)
  unsigned short* Xlo = Xhi + NQ;                    // 8 MB (optional)
  // phase-2 region (overlaps split region; used only after the GEMM)
  float* Mv     = Vt + NQ;                           // 256 KB
  float* vmeanM = Mv + (size_t)B_ * H_ * L_;         // 8 KB
  float* baseB  = vmeanM + B_ * D_;                  // 8 KB
  int*   topIdx = (int*)(baseB + B_ * D_);           // 5 KB
  // vmean accumulator lives in d_out[0:2048].
  float* vmAcc = out;

  const bool xsplit = ws_size >= ((size_t)76 << 20);
  const int nW = 3 * D_ * D_ / 4;
  const int nX = (int)(NQ / 4);

  if (xsplit) {
    split_all<<<dim3((nW + nX) / 256), dim3(256), 0, stream>>>(
        Wq, Wkv, x, Whi, Wlo, Xhi, Xlo, vmAcc, nW);
    gemm_qkv_16w<<<dim3(B_ * L_ / 256, 3 * D_ / 192), dim3(1024), 0,
                   stream>>>(Xhi, Xlo, Whi, Wlo, bq, bkv, Q, Kt, Vt, vmAcc);
  } else {
    split_all<<<dim3(nW / 256), dim3(256), 0, stream>>>(Wq, Wkv, x, Whi, Wlo,
                                                        Xhi, Xlo, vmAcc, nW);
    gemm_qkv_fallback<<<dim3(3 * D_ / 128, B_ * L_ / 128), dim3(256), 0,
                        stream>>>(x, Whi, Wlo, bq, bkv, Q, Kt, Vt, vmAcc);
  }
  sample_base<<<dim3(4096 + B_ * 16), dim3(256), 0, stream>>>(
      Q, Kt, idx, Mv, vmAcc, Wout, bout, baseB, vmeanM);
  bcast_topk<<<dim3(4096 + B_ * H_), dim3(256), 0, stream>>>(baseB, out, Mv,
                                                             topIdx);
  attn_corr<<<dim3(32, 8), dim3(256), 0, stream>>>(Q, Kt, Vt, topIdx, vmeanM,
                                                   Wout, out);
}

// Round 20
// 233.453 us; speedup vs baseline: 1.0345x; 1.0345x over previous
//
#include <hip/hip_runtime.h>
#include <math.h>

// Problem constants (B=2, L=2048, D=1024, H=16, FACTOR=5)
#define B_ 2
#define L_ 2048
#define D_ 1024
#define H_ 16
#define DH_ 64
#define U_ 40
#define SCALE_ 0.125f

typedef __attribute__((ext_vector_type(8))) short short8v;            // 8 bf16
typedef __attribute__((ext_vector_type(4))) float f32x4;
typedef __attribute__((ext_vector_type(4))) unsigned short ushort4v;  // 8 B

static __device__ __forceinline__ unsigned short bf16_rne(float f) {
  unsigned int u = __float_as_uint(f);
  u += 0x7fff + ((u >> 16) & 1);
  return (unsigned short)(u >> 16);
}
static __device__ __forceinline__ float bf16_f32(unsigned short h) {
  return __uint_as_float(((unsigned int)h) << 16);
}

// Async global->LDS, 16 B per lane.
static __device__ __forceinline__ void gload16(const unsigned short* src,
                                               unsigned short* lds) {
  __builtin_amdgcn_global_load_lds(
      (const __attribute__((address_space(1))) void*)src,
      (__attribute__((address_space(3))) void*)lds, 16, 0, 0);
}

#define BARRIER                                  \
  do {                                           \
    asm volatile("" ::: "memory");               \
    __builtin_amdgcn_s_barrier();                \
    asm volatile("" ::: "memory");               \
  } while (0)
// Rule #18: force all LDS reads to retire and pin instruction movement.
#define LGKM0                                          \
  do {                                                 \
    asm volatile("s_waitcnt lgkmcnt(0)" ::: "memory"); \
    __builtin_amdgcn_sched_barrier(0);                 \
  } while (0)

// ---------------------------------------------------------------------------
// Pre-split f32 -> (hi,lo) bf16 for W=[Wq;Wkv] (quads [0,nW)) and X (rest).
// Block 0 additionally zeroes the vmean accumulator (in d_out[0:2048]).
// ---------------------------------------------------------------------------
__global__ __launch_bounds__(256) void split_all(
    const float* __restrict__ Wq, const float* __restrict__ Wkv,
    const float* __restrict__ X, unsigned short* __restrict__ Whi,
    unsigned short* __restrict__ Wlo, unsigned short* __restrict__ Xhi,
    unsigned short* __restrict__ Xlo, float* __restrict__ vmAcc, int nW) {
  if (blockIdx.x == 0) {
    for (int z = threadIdx.x; z < B_ * D_; z += 256) vmAcc[z] = 0.f;
  }
  int i = blockIdx.x * 256 + threadIdx.x;
  const int nq_q = (D_ * D_) / 4;
  float4 v;
  unsigned short *hi, *lo;
  int off;
  if (i < nW) {
    v = (i < nq_q) ? ((const float4*)Wq)[i] : ((const float4*)Wkv)[i - nq_q];
    hi = Whi; lo = Wlo; off = i;
  } else {
    off = i - nW;
    v = ((const float4*)X)[off];
    hi = Xhi; lo = Xlo;
  }
  float vv[4] = {v.x, v.y, v.z, v.w};
  ushort4v h, l;
#pragma unroll
  for (int e = 0; e < 4; ++e) {
    unsigned short hh = bf16_rne(vv[e]);
    h[e] = hh;
    l[e] = bf16_rne(vv[e] - bf16_f32(hh));
  }
  ((ushort4v*)hi)[off] = h;
  ((ushort4v*)lo)[off] = l;
}

// ---------------------------------------------------------------------------
// Pipelined split-bf16 MFMA GEMM (R18 version restored): 256x192 tile,
// 16 waves, 2 LDS buffers, 1 barrier/step. Grid (col=x, row=y).
// ---------------------------------------------------------------------------
__global__ __launch_bounds__(1024, 1) void gemm_qkv_16w(
    const unsigned short* __restrict__ Xhi,
    const unsigned short* __restrict__ Xlo,
    const unsigned short* __restrict__ Whi,
    const unsigned short* __restrict__ Wlo,
    const float* __restrict__ bq, const float* __restrict__ bkv,
    float* __restrict__ Qo, float* __restrict__ Ko, float* __restrict__ Vo,
    float* __restrict__ vmAcc) {
  __shared__ unsigned short LDS[2][28672];
  const int tid = threadIdx.x;
  const int lane = tid & 63;
  const int wave = tid >> 6;
  const int wm = wave >> 2, wn = wave & 3;
  const int row0 = blockIdx.y * 256;
  const int col0 = blockIdx.x * 192;

  f32x4 acc[4][3] = {};

  const unsigned short* gsrc[4];
  int gcv[4];
#pragma unroll
  for (int r = 0; r < 4; ++r) {
    int c = (r < 3) ? (wave + 16 * r) : (48 + (wave & 7));
    gcv[r] = c;
    const unsigned short* base;
    int rowin, isA;
    if (c < 16)      { base = Xhi; rowin = c * 16;        isA = 1; }
    else if (c < 32) { base = Xlo; rowin = (c - 16) * 16; isA = 1; }
    else if (c < 44) { base = Whi; rowin = (c - 32) * 16; isA = 0; }
    else             { base = Wlo; rowin = (c - 44) * 16; isA = 0; }
    rowin += (lane >> 2);
    int grow = (isA ? row0 : col0) + rowin;
    int seg = (lane & 3) ^ ((rowin >> 1) & 3);
    gsrc[r] = base + (size_t)grow * D_ + seg * 8;
  }

  const int fr_r = lane & 15;
  const int hs = lane >> 4;

#define STG_ALL(k0s, Ls)                                        \
  do {                                                          \
    gload16(gsrc[0] + (k0s), (Ls) + gcv[0] * 512);              \
    gload16(gsrc[1] + (k0s), (Ls) + gcv[1] * 512);              \
    gload16(gsrc[2] + (k0s), (Ls) + gcv[2] * 512);              \
    if (wave < 8) gload16(gsrc[3] + (k0s), (Ls) + gcv[3] * 512);\
  } while (0)

  STG_ALL(0, &LDS[0][0]);
  asm volatile("s_waitcnt vmcnt(0)" ::: "memory");
  BARRIER;

  for (int ks = 0; ks < 32; ++ks) {
    unsigned short* Lc = &LDS[ks & 1][0];
    unsigned short* Ls = &LDS[(ks + 1) & 1][0];
    if (ks < 31) STG_ALL((ks + 1) * 32, Ls);

    short8v a_h[4], a_l[4], b_h[3], b_l[3];
#pragma unroll
    for (int ni = 0; ni < 3; ++ni) {
      int rc = wn * 48 + ni * 16 + fr_r;
      int off = rc * 32 + ((hs ^ ((rc >> 1) & 3)) << 3);
      b_h[ni] = *(const short8v*)&Lc[16384 + off];
      b_l[ni] = *(const short8v*)&Lc[22528 + off];
    }
#pragma unroll
    for (int mi = 0; mi < 4; ++mi) {
      int rr = wm * 64 + mi * 16 + fr_r;
      int off = rr * 32 + ((hs ^ ((rr >> 1) & 3)) << 3);
      a_h[mi] = *(const short8v*)&Lc[off];
      a_l[mi] = *(const short8v*)&Lc[8192 + off];
    }

#pragma unroll
    for (int mi = 0; mi < 4; ++mi)
#pragma unroll
      for (int ni = 0; ni < 3; ++ni) {
        acc[mi][ni] = __builtin_amdgcn_mfma_f32_16x16x32_bf16(
            a_h[mi], b_h[ni], acc[mi][ni], 0, 0, 0);
        acc[mi][ni] = __builtin_amdgcn_mfma_f32_16x16x32_bf16(
            a_h[mi], b_l[ni], acc[mi][ni], 0, 0, 0);
        acc[mi][ni] = __builtin_amdgcn_mfma_f32_16x16x32_bf16(
            a_l[mi], b_h[ni], acc[mi][ni], 0, 0, 0);
      }

    LGKM0;
    asm volatile("s_waitcnt vmcnt(0)" ::: "memory");
    BARRIER;
  }

  // Epilogue: C/D layout col=lane&15, row=(lane>>4)*4+reg.
#pragma unroll
  for (int ni = 0; ni < 3; ++ni) {
    int c = col0 + wn * 48 + ni * 16 + (lane & 15);
    int which = c >> 10;
    int jj = c & (D_ - 1);
    int h = jj >> 6, dh = jj & 63;
    float bias = (c < D_) ? bq[c] : bkv[c - D_];
    float* dst = (which == 0) ? Qo : ((which == 1) ? Ko : Vo);
#pragma unroll
    for (int mi = 0; mi < 4; ++mi) {
#pragma unroll
      for (int reg = 0; reg < 4; ++reg) {
        int r = row0 + wm * 64 + mi * 16 + ((lane >> 4) << 2) + reg;
        int b = r >> 11, l = r & (L_ - 1);
        dst[(((size_t)b * H_ + h) * L_ + l) * DH_ + dh] =
            acc[mi][ni][reg] + bias;
      }
    }
    if (which == 2) {  // vmean partial: sum over this wave's 64 rows
      float s = 0.f;
#pragma unroll
      for (int mi = 0; mi < 4; ++mi)
#pragma unroll
        for (int reg = 0; reg < 4; ++reg) s += acc[mi][ni][reg];
      s += __shfl_xor(s, 16);
      s += __shfl_xor(s, 32);
      if ((lane >> 4) == 0)
        atomicAdd(&vmAcc[(row0 >> 11) * D_ + jj], s + 64.0f * bias);
    }
  }
#undef STG_ALL
}

// ---------------------------------------------------------------------------
// Fallback GEMM (R10 structure) — used only when ws can't hold Xhi/Xlo.
// ---------------------------------------------------------------------------
__global__ __launch_bounds__(256) void gemm_qkv_fallback(
    const float* __restrict__ X,
    const unsigned short* __restrict__ Whi,
    const unsigned short* __restrict__ Wlo,
    const float* __restrict__ bq, const float* __restrict__ bkv,
    float* __restrict__ Qo, float* __restrict__ Ko, float* __restrict__ Vo,
    float* __restrict__ vmAcc) {
  __shared__ unsigned short Ah[128 * 32];
  __shared__ unsigned short Al[128 * 32];
  __shared__ unsigned short Bh[128 * 32];
  __shared__ unsigned short Bl[128 * 32];
  const int tid = threadIdx.x;
  const int lane = tid & 63;
  const int wave = tid >> 6;
  const int wm = wave >> 1, wn = wave & 1;
  const int row0 = blockIdx.y * 128;
  const int col0 = blockIdx.x * 128;

  f32x4 acc[4][4] = {};

  const int grow = lane >> 2;
  const int gg = lane & 3;

  for (int k0 = 0; k0 < D_; k0 += 32) {
#pragma unroll
    for (int j = 0; j < 2; ++j) {
      int c = wave + 4 * j;
      int row = c * 16 + grow;
      int gsrc = (gg ^ ((row >> 1) & 3)) << 3;
      size_t soffB = (size_t)(col0 + row) * D_ + k0 + gsrc;
      gload16(Whi + soffB, Bh + c * 512);
      gload16(Wlo + soffB, Bl + c * 512);
    }
#pragma unroll
    for (int rep = 0; rep < 2; ++rep) {
      int task = tid + rep * 256;
      int row = task >> 2;
      int gt = task & 3;
      const float* s = X + (size_t)(row0 + row) * D_ + k0 + gt * 8;
      float4 a0 = *(const float4*)s;
      float4 a1 = *(const float4*)(s + 4);
      float av[8] = {a0.x, a0.y, a0.z, a0.w, a1.x, a1.y, a1.z, a1.w};
      short8v hseg, lseg;
#pragma unroll
      for (int e = 0; e < 8; ++e) {
        unsigned short hh = bf16_rne(av[e]);
        hseg[e] = (short)hh;
        lseg[e] = (short)bf16_rne(av[e] - bf16_f32(hh));
      }
      int dst = row * 32 + ((gt ^ ((row >> 1) & 3)) << 3);
      *(short8v*)&Ah[dst] = hseg;
      *(short8v*)&Al[dst] = lseg;
    }
    __syncthreads();

    short8v a_h[4], a_l[4], b_h[4], b_l[4];
    const int hs = lane >> 4;
#pragma unroll
    for (int mi = 0; mi < 4; ++mi) {
      int rr = wm * 64 + mi * 16 + (lane & 15);
      int off = rr * 32 + ((hs ^ ((rr >> 1) & 3)) << 3);
      a_h[mi] = *(const short8v*)&Ah[off];
      a_l[mi] = *(const short8v*)&Al[off];
    }
#pragma unroll
    for (int ni = 0; ni < 4; ++ni) {
      int rc = wn * 64 + ni * 16 + (lane & 15);
      int off = rc * 32 + ((hs ^ ((rc >> 1) & 3)) << 3);
      b_h[ni] = *(const short8v*)&Bh[off];
      b_l[ni] = *(const short8v*)&Bl[off];
    }
#pragma unroll
    for (int mi = 0; mi < 4; ++mi)
#pragma unroll
      for (int ni = 0; ni < 4; ++ni) {
        acc[mi][ni] = __builtin_amdgcn_mfma_f32_16x16x32_bf16(
            a_h[mi], b_h[ni], acc[mi][ni], 0, 0, 0);
        acc[mi][ni] = __builtin_amdgcn_mfma_f32_16x16x32_bf16(
            a_h[mi], b_l[ni], acc[mi][ni], 0, 0, 0);
        acc[mi][ni] = __builtin_amdgcn_mfma_f32_16x16x32_bf16(
            a_l[mi], b_h[ni], acc[mi][ni], 0, 0, 0);
      }
    __syncthreads();
  }

#pragma unroll
  for (int ni = 0; ni < 4; ++ni) {
    int c = col0 + wn * 64 + ni * 16 + (lane & 15);
    int which = c >> 10;
    int jj = c & (D_ - 1);
    int h = jj >> 6, dh = jj & 63;
    float bias = (c < D_) ? bq[c] : bkv[c - D_];
    float* dst = (which == 0) ? Qo : ((which == 1) ? Ko : Vo);
#pragma unroll
    for (int mi = 0; mi < 4; ++mi) {
#pragma unroll
      for (int reg = 0; reg < 4; ++reg) {
        int r = row0 + wm * 64 + mi * 16 + ((lane >> 4) << 2) + reg;
        int b = r >> 11, l = r & (L_ - 1);
        dst[(((size_t)b * H_ + h) * L_ + l) * DH_ + dh] =
            acc[mi][ni][reg] + bias;
      }
    }
    if (which == 2) {
      float s = 0.f;
#pragma unroll
      for (int mi = 0; mi < 4; ++mi)
#pragma unroll
        for (int reg = 0; reg < 4; ++reg) s += acc[mi][ni][reg];
      s += __shfl_xor(s, 16);
      s += __shfl_xor(s, 32);
      if ((lane >> 4) == 0)
        atomicAdd(&vmAcc[(row0 >> 11) * D_ + jj], s + 64.0f * bias);
    }
  }
}

// ---------------------------------------------------------------------------
// Merged kernel A: blocks [0,4096) = sample_m; blocks [4096,4128) = base.
// sample_m: bh = bid&31 -> all 128 blocks of one bh share an XCD.
// ---------------------------------------------------------------------------
__global__ __launch_bounds__(256) void sample_base(
    const float* __restrict__ Q, const float* __restrict__ Kt,
    const int* __restrict__ idx, float* __restrict__ Mv,
    const float* __restrict__ vmAcc, const float* __restrict__ Wout,
    const float* __restrict__ bout, float* __restrict__ baseOut,
    float* __restrict__ vmeanM) {
  int t = threadIdx.x;
  if (blockIdx.x < 4096) {
    int bh = blockIdx.x & 31;
    int chunk = blockIdx.x >> 5;
    int w = t >> 6, lane = t & 63;
    int subl = lane >> 4, d16 = lane & 15;
    int l = chunk * 16 + w * 4 + subl;
    int gl = bh * L_ + l;
    const float4* Kb4 = (const float4*)(Kt + (size_t)bh * L_ * DH_);
    float4 q4 = ((const float4*)(Q + (size_t)gl * DH_))[d16];
    const int* irow = idx + l * U_;
    float mx = -INFINITY, sm = 0.f;
#pragma unroll 8
    for (int u = 0; u < U_; ++u) {
      int kl = irow[u];
      float4 k4 = Kb4[kl * 16 + d16];
      float p = q4.x * k4.x + q4.y * k4.y + q4.z * k4.z + q4.w * k4.w;
      p += __shfl_xor(p, 1);
      p += __shfl_xor(p, 2);
      p += __shfl_xor(p, 4);
      p += __shfl_xor(p, 8);
      mx = fmaxf(mx, p);
      sm += p;
    }
    if (d16 == 0) Mv[gl] = mx - sm * (1.0f / U_);
  } else {
    int bid = blockIdx.x - 4096;
    int b = bid >> 4, jc = bid & 15;
    int j = jc * 64 + (t & 63);
    int isl = t >> 6;
    __shared__ float vm[D_];
    __shared__ float red[256];
    for (int i = t; i < D_; i += 256) vm[i] = vmAcc[b * D_ + i] * (1.0f / L_);
    __syncthreads();
    if (jc == 0)
      for (int i = t; i < D_; i += 256) vmeanM[b * D_ + i] = vm[i];
    float s = 0.f;
    const float* wr = Wout + (size_t)j * D_ + isl * 256;
    const float* vv = vm + isl * 256;
    for (int i = 0; i < 256; i += 4) {
      float4 w = *(const float4*)(wr + i);
      s += vv[i] * w.x + vv[i + 1] * w.y + vv[i + 2] * w.z + vv[i + 3] * w.w;
    }
    red[t] = s;
    __syncthreads();
    if (isl == 0)
      baseOut[b * D_ + j] =
          red[t] + red[t + 64] + red[t + 128] + red[t + 192] + bout[j];
  }
}

// ---------------------------------------------------------------------------
// Merged kernel B: blocks [0,4096) = bcast_out; [4096,4128) = topk.
// ---------------------------------------------------------------------------
__global__ __launch_bounds__(256) void bcast_topk(
    const float* __restrict__ baseIn, float* __restrict__ out,
    const float* __restrict__ Mv, int* __restrict__ topIdx) {
  int t = threadIdx.x;
  if (blockIdx.x < 4096) {
    size_t i4 = (size_t)blockIdx.x * 256 + t;
    size_t i = i4 * 4;
    int b = (int)(i >> 21);
    int col = (int)(i & (D_ - 1));
    *(float4*)(out + i) = *(const float4*)(baseIn + b * D_ + col);
  } else {
    __shared__ float vals[L_];
    int lane = t & 63;
    int bh = blockIdx.x - 4096;
    for (int j = t; j < L_; j += 256) vals[j] = Mv[(size_t)bh * L_ + j];
    __syncthreads();
    for (int it = 0; it < U_; ++it) {
      float bv = -INFINITY;
      int bi = 0x7fffffff;
      for (int j = 0; j < 32; ++j) {
        int i = j * 64 + lane;
        float v = vals[i];
        if (v > bv) { bv = v; bi = i; }
      }
#pragma unroll
      for (int off = 32; off > 0; off >>= 1) {
        float ov = __shfl_xor(bv, off);
        int oi = __shfl_xor(bi, off);
        if (ov > bv || (ov == bv && oi < bi)) { bv = ov; bi = oi; }
      }
      if (t == 0) topIdx[bh * U_ + it] = bi;
      vals[bi] = -INFINITY;  // all waves compute identical bi
      __syncthreads();
    }
  }
}

// ---------------------------------------------------------------------------
// Fused attention + output correction. Grid (32, 8), 512 THREADS (8 waves):
// halves the serial QK chain (4 passes of 512 keys), splits PV 8 ways
// (64 iters/wave), corr GEMV over 8-lane segments. Attacks the 10.7%
// occupancy latency-bound profile seen in R19.
// ---------------------------------------------------------------------------
__global__ __launch_bounds__(512) void attn_corr(
    const float* __restrict__ Q, const float* __restrict__ Kt,
    const float* __restrict__ Vt, const int* __restrict__ topIdx,
    const float* __restrict__ vmeanM, const float* __restrict__ Wout,
    float* __restrict__ out) {
  int bh = blockIdx.x;  // 0..31 (XCD key)
  int qc = blockIdx.y;  // 0..7 (5 queries each)
  int b = bh >> 4, h = bh & (H_ - 1);
  __shared__ float Qs[5][DH_];
  __shared__ float Sv[5][L_];        // 40 KB
  __shared__ float part[8][5][DH_];  // 10 KB
  __shared__ float inv[5];
  __shared__ float dv[5][DH_];
  __shared__ int lq[5];
  int t = threadIdx.x;               // 0..511
  int lane = t & 63, w = t >> 6;     // 8 waves

  if (t < 80) {
    int q = t >> 4, c4 = t & 15;
    int ql = topIdx[bh * U_ + qc * 5 + q];
    *(float4*)&Qs[q][c4 * 4] =
        *(const float4*)&Q[((size_t)bh * L_ + ql) * DH_ + c4 * 4];
  }
  if (t < 5) lq[t] = topIdx[bh * U_ + qc * 5 + t];
  __syncthreads();

  // ---- QK: 4 passes x 512 keys
  const float* Kb = Kt + (size_t)bh * L_ * DH_;
  for (int kc = 0; kc < 4; ++kc) {
    int key = kc * 512 + t;
    const float* kr = Kb + (size_t)key * DH_;
    float acc[5];
#pragma unroll
    for (int q = 0; q < 5; ++q) acc[q] = 0.f;
#pragma unroll
    for (int i4 = 0; i4 < 16; ++i4) {
      float4 k4 = *(const float4*)(kr + i4 * 4);
#pragma unroll
      for (int q = 0; q < 5; ++q) {
        float4 qv = *(const float4*)&Qs[q][i4 * 4];
        acc[q] += k4.x * qv.x + k4.y * qv.y + k4.z * qv.z + k4.w * qv.w;
      }
    }
#pragma unroll
    for (int q = 0; q < 5; ++q) Sv[q][key] = acc[q] * SCALE_;
  }
  __syncthreads();

  // ---- softmax: waves 0-4 own rows 0-4 (same arithmetic as before)
  if (w < 5) {
    int r = w;
    float mx = -INFINITY;
    for (int j = 0; j < 32; ++j) mx = fmaxf(mx, Sv[r][j * 64 + lane]);
#pragma unroll
    for (int off = 1; off < 64; off <<= 1)
      mx = fmaxf(mx, __shfl_xor(mx, off));
    float sm = 0.f;
    for (int j = 0; j < 32; ++j) {
      float e = __expf(Sv[r][j * 64 + lane] - mx);
      Sv[r][j * 64 + lane] = e;
      sm += e;
    }
#pragma unroll
    for (int off = 1; off < 64; off <<= 1) sm += __shfl_xor(sm, off);
    if (lane == 0) inv[r] = 1.0f / sm;
  }
  __syncthreads();

  // ---- PV: wave w covers keys [w*256, w*256+256), lane = dh
  {
    const float* vb = Vt + ((size_t)bh * L_ + w * 256) * DH_ + lane;
    float acc[5];
#pragma unroll
    for (int q = 0; q < 5; ++q) acc[q] = 0.f;
    for (int k4 = 0; k4 < 64; ++k4) {
      float v0 = vb[(k4 * 4 + 0) * DH_];
      float v1 = vb[(k4 * 4 + 1) * DH_];
      float v2 = vb[(k4 * 4 + 2) * DH_];
      float v3 = vb[(k4 * 4 + 3) * DH_];
      int k = w * 256 + k4 * 4;
#pragma unroll
      for (int q = 0; q < 5; ++q) {
        float4 p4 = *(const float4*)&Sv[q][k];
        acc[q] += p4.x * v0 + p4.y * v1 + p4.z * v2 + p4.w * v3;
      }
    }
#pragma unroll
    for (int q = 0; q < 5; ++q) part[w][q][lane] = acc[q];
  }
  __syncthreads();

  // dv = ctx - vmean (merge 8 partials)
  for (int o = t; o < 5 * DH_; o += 512) {
    int q = o >> 6, dh = o & 63;
    float s = ((part[0][q][dh] + part[1][q][dh]) +
               (part[2][q][dh] + part[3][q][dh])) +
              ((part[4][q][dh] + part[5][q][dh]) +
               (part[6][q][dh] + part[7][q][dh]));
    dv[q][dh] = s * inv[q] - vmeanM[b * D_ + h * DH_ + dh];
  }
  __syncthreads();

  // ---- correction GEMV: 8-lane segments (sub = t&7 covers 8 of 64 dims)
  int sub = t & 7;
  int jbase = t >> 3;  // 0..63
#pragma unroll
  for (int jc = 0; jc < 16; ++jc) {
    int j = jc * 64 + jbase;
    const float* wr = Wout + (size_t)j * D_ + h * DH_ + sub * 8;
    float4 w0 = ((const float4*)wr)[0];
    float4 w1 = ((const float4*)wr)[1];
#pragma unroll
    for (int q = 0; q < 5; ++q) {
      const float* dq = &dv[q][sub * 8];
      float s = dq[0] * w0.x + dq[1] * w0.y + dq[2] * w0.z + dq[3] * w0.w +
                dq[4] * w1.x + dq[5] * w1.y + dq[6] * w1.z + dq[7] * w1.w;
      s += __shfl_xor(s, 1);
      s += __shfl_xor(s, 2);
      s += __shfl_xor(s, 4);
      if (sub == 0)
        atomicAdd(out + ((size_t)b * L_ + lq[q]) * D_ + j, s);
    }
  }
}

// ---------------------------------------------------------------------------
extern "C" void kernel_launch(void* const* d_in, const int* in_sizes, int n_in,
                              void* d_out, int out_size, void* d_ws,
                              size_t ws_size, hipStream_t stream) {
  const float* x    = (const float*)d_in[0];
  const float* Wq   = (const float*)d_in[1];
  const float* bq   = (const float*)d_in[2];
  const float* Wkv  = (const float*)d_in[3];
  const float* bkv  = (const float*)d_in[4];
  const float* Wout = (const float*)d_in[5];
  const float* bout = (const float*)d_in[6];
  const int*   idx  = (const int*)d_in[7];
  float* out = (float*)d_out;

  float* ws = (float*)d_ws;
  const size_t NQ = (size_t)B_ * H_ * L_ * DH_;  // 4,194,304 floats
  float* Q  = ws;
  float* Kt = Q + NQ;
  float* Vt = Kt + NQ;
  // W/X split region (live only through the GEMM)
  unsigned short* Whi = (unsigned short*)(Vt + NQ);  // 6 MB
  unsigned short* Wlo = Whi + (size_t)3 * D_ * D_;   // 6 MB
  unsigned short* Xhi = Wlo + (size_t)3 * D_ * D_;   // 8 MB (optional)
  unsigned short* Xlo = Xhi + NQ;                    // 8 MB (optional)
  // phase-2 region (overlaps split region; used only after the GEMM)
  float* Mv     = Vt + NQ;                           // 256 KB
  float* vmeanM = Mv + (size_t)B_ * H_ * L_;         // 8 KB
  float* baseB  = vmeanM + B_ * D_;                  // 8 KB
  int*   topIdx = (int*)(baseB + B_ * D_);           // 5 KB
  // vmean accumulator lives in d_out[0:2048].
  float* vmAcc = out;

  const bool xsplit = ws_size >= ((size_t)76 << 20);
  const int nW = 3 * D_ * D_ / 4;
  const int nX = (int)(NQ / 4);

  if (xsplit) {
    split_all<<<dim3((nW + nX) / 256), dim3(256), 0, stream>>>(
        Wq, Wkv, x, Whi, Wlo, Xhi, Xlo, vmAcc, nW);
    gemm_qkv_16w<<<dim3(3 * D_ / 192, B_ * L_ / 256), dim3(1024), 0,
                   stream>>>(Xhi, Xlo, Whi, Wlo, bq, bkv, Q, Kt, Vt, vmAcc);
  } else {
    split_all<<<dim3(nW / 256), dim3(256), 0, stream>>>(Wq, Wkv, x, Whi, Wlo,
                                                        Xhi, Xlo, vmAcc, nW);
    gemm_qkv_fallback<<<dim3(3 * D_ / 128, B_ * L_ / 128), dim3(256), 0,
                        stream>>>(x, Whi, Wlo, bq, bkv, Q, Kt, Vt, vmAcc);
  }
  sample_base<<<dim3(4096 + B_ * 16), dim3(256), 0, stream>>>(
      Q, Kt, idx, Mv, vmAcc, Wout, bout, baseB, vmeanM);
  bcast_topk<<<dim3(4096 + B_ * H_), dim3(256), 0, stream>>>(baseB, out, Mv,
                                                             topIdx);
  attn_corr<<<dim3(32, 8), dim3(512), 0, stream>>>(Q, Kt, Vt, topIdx, vmeanM,
                                                   Wout, out);
}

// Round 21
// 216.179 us; speedup vs baseline: 1.1172x; 1.0799x over previous
//
#include <hip/hip_runtime.h>
#include <math.h>

// Problem constants (B=2, L=2048, D=1024, H=16, FACTOR=5)
#define B_ 2
#define L_ 2048
#define D_ 1024
#define H_ 16
#define DH_ 64
#define U_ 40
#define SCALE_ 0.125f

typedef __attribute__((ext_vector_type(8))) short short8v;            // 8 bf16
typedef __attribute__((ext_vector_type(4))) float f32x4;
typedef __attribute__((ext_vector_type(4))) unsigned short ushort4v;  // 8 B

static __device__ __forceinline__ unsigned short bf16_rne(float f) {
  unsigned int u = __float_as_uint(f);
  u += 0x7fff + ((u >> 16) & 1);
  return (unsigned short)(u >> 16);
}
static __device__ __forceinline__ float bf16_f32(unsigned short h) {
  return __uint_as_float(((unsigned int)h) << 16);
}

// Async global->LDS, 16 B per lane.
static __device__ __forceinline__ void gload16(const unsigned short* src,
                                               unsigned short* lds) {
  __builtin_amdgcn_global_load_lds(
      (const __attribute__((address_space(1))) void*)src,
      (__attribute__((address_space(3))) void*)lds, 16, 0, 0);
}

#define BARRIER                                  \
  do {                                           \
    asm volatile("" ::: "memory");               \
    __builtin_amdgcn_s_barrier();                \
    asm volatile("" ::: "memory");               \
  } while (0)
// Rule #18: force all LDS reads to retire and pin instruction movement.
#define LGKM0                                          \
  do {                                                 \
    asm volatile("s_waitcnt lgkmcnt(0)" ::: "memory"); \
    __builtin_amdgcn_sched_barrier(0);                 \
  } while (0)

// ---------------------------------------------------------------------------
// Pre-split f32 -> (hi,lo) bf16 for W=[Wq;Wkv] (quads [0,nW)) and X (rest).
// Block 0 additionally zeroes the vmean accumulator (in d_out[0:2048]).
// ---------------------------------------------------------------------------
__global__ __launch_bounds__(256) void split_all(
    const float* __restrict__ Wq, const float* __restrict__ Wkv,
    const float* __restrict__ X, unsigned short* __restrict__ Whi,
    unsigned short* __restrict__ Wlo, unsigned short* __restrict__ Xhi,
    unsigned short* __restrict__ Xlo, float* __restrict__ vmAcc, int nW) {
  if (blockIdx.x == 0) {
    for (int z = threadIdx.x; z < B_ * D_; z += 256) vmAcc[z] = 0.f;
  }
  int i = blockIdx.x * 256 + threadIdx.x;
  const int nq_q = (D_ * D_) / 4;
  float4 v;
  unsigned short *hi, *lo;
  int off;
  if (i < nW) {
    v = (i < nq_q) ? ((const float4*)Wq)[i] : ((const float4*)Wkv)[i - nq_q];
    hi = Whi; lo = Wlo; off = i;
  } else {
    off = i - nW;
    v = ((const float4*)X)[off];
    hi = Xhi; lo = Xlo;
  }
  float vv[4] = {v.x, v.y, v.z, v.w};
  ushort4v h, l;
#pragma unroll
  for (int e = 0; e < 4; ++e) {
    unsigned short hh = bf16_rne(vv[e]);
    h[e] = hh;
    l[e] = bf16_rne(vv[e] - bf16_f32(hh));
  }
  ((ushort4v*)hi)[off] = h;
  ((ushort4v*)lo)[off] = l;
}

// ---------------------------------------------------------------------------
// Pipelined split-bf16 MFMA GEMM, tile 128x384, BK=32, 16 waves (4Mx4N,
// per-wave 32x96 = 2x6 frags). Per-wave LDS reads/step: 16 b128 (vs 22 at
// 256x192) with identical MFMA count -> lower LDS-serve floor. 2 buffers x
// 64 KB. Staging = exactly 4 x 1KB gload calls per wave (64 total).
// Grid (8 N-tiles, 32 M-tiles): XCD = N-tile&7 (W panel L2-resident).
// ---------------------------------------------------------------------------
__global__ __launch_bounds__(1024, 1) void gemm_qkv_16w(
    const unsigned short* __restrict__ Xhi,
    const unsigned short* __restrict__ Xlo,
    const unsigned short* __restrict__ Whi,
    const unsigned short* __restrict__ Wlo,
    const float* __restrict__ bq, const float* __restrict__ bkv,
    float* __restrict__ Qo, float* __restrict__ Ko, float* __restrict__ Vo,
    float* __restrict__ vmAcc) {
  // Per buffer (shorts): Ahi[128*32]@0, Alo@4096, Bhi[384*32]@8192,
  // Blo@20480; total 32768 shorts = 64 KB. 2 buffers = 128 KB.
  __shared__ unsigned short LDS[2][32768];
  const int tid = threadIdx.x;  // 0..1023
  const int lane = tid & 63;
  const int wave = tid >> 6;            // 0..15
  const int wm = wave >> 2, wn = wave & 3;
  const int row0 = blockIdx.y * 128;    // M = 4096 -> 32 tiles
  const int col0 = blockIdx.x * 384;    // N = 3072 -> 8 tiles (XCD key)

  f32x4 acc[2][6] = {};

  // Staging map: call c = wave + 16*r, r=0..3 (c = 0..63, each once).
  // c<8: Ahi rows c*16 ; c<16: Alo ; c<40: Bhi rows (c-16)*16 ; else Blo.
  const unsigned short* gsrc[4];
  int gcv[4];
#pragma unroll
  for (int r = 0; r < 4; ++r) {
    int c = wave + 16 * r;
    gcv[r] = c;
    const unsigned short* base;
    int rowin, isA;
    if (c < 8)       { base = Xhi; rowin = c * 16;        isA = 1; }
    else if (c < 16) { base = Xlo; rowin = (c - 8) * 16;  isA = 1; }
    else if (c < 40) { base = Whi; rowin = (c - 16) * 16; isA = 0; }
    else             { base = Wlo; rowin = (c - 40) * 16; isA = 0; }
    rowin += (lane >> 2);
    int grow = (isA ? row0 : col0) + rowin;
    int seg = (lane & 3) ^ ((rowin >> 1) & 3);
    gsrc[r] = base + (size_t)grow * D_ + seg * 8;
  }

  const int fr_r = lane & 15;
  const int hs = lane >> 4;

#define STG_ALL(k0s, Ls)                            \
  do {                                              \
    gload16(gsrc[0] + (k0s), (Ls) + gcv[0] * 512);  \
    gload16(gsrc[1] + (k0s), (Ls) + gcv[1] * 512);  \
    gload16(gsrc[2] + (k0s), (Ls) + gcv[2] * 512);  \
    gload16(gsrc[3] + (k0s), (Ls) + gcv[3] * 512);  \
  } while (0)

  STG_ALL(0, &LDS[0][0]);
  asm volatile("s_waitcnt vmcnt(0)" ::: "memory");
  BARRIER;

  for (int ks = 0; ks < 32; ++ks) {
    unsigned short* Lc = &LDS[ks & 1][0];
    unsigned short* Ls = &LDS[(ks + 1) & 1][0];
    if (ks < 31) STG_ALL((ks + 1) * 32, Ls);

    short8v a_h[2], a_l[2], b_h[6], b_l[6];
#pragma unroll
    for (int ni = 0; ni < 6; ++ni) {
      int rc = wn * 96 + ni * 16 + fr_r;
      int off = rc * 32 + ((hs ^ ((rc >> 1) & 3)) << 3);
      b_h[ni] = *(const short8v*)&Lc[8192 + off];
      b_l[ni] = *(const short8v*)&Lc[20480 + off];
    }
#pragma unroll
    for (int mi = 0; mi < 2; ++mi) {
      int rr = wm * 32 + mi * 16 + fr_r;
      int off = rr * 32 + ((hs ^ ((rr >> 1) & 3)) << 3);
      a_h[mi] = *(const short8v*)&Lc[off];
      a_l[mi] = *(const short8v*)&Lc[4096 + off];
    }

#pragma unroll
    for (int mi = 0; mi < 2; ++mi)
#pragma unroll
      for (int ni = 0; ni < 6; ++ni) {
        acc[mi][ni] = __builtin_amdgcn_mfma_f32_16x16x32_bf16(
            a_h[mi], b_h[ni], acc[mi][ni], 0, 0, 0);
        acc[mi][ni] = __builtin_amdgcn_mfma_f32_16x16x32_bf16(
            a_h[mi], b_l[ni], acc[mi][ni], 0, 0, 0);
        acc[mi][ni] = __builtin_amdgcn_mfma_f32_16x16x32_bf16(
            a_l[mi], b_h[ni], acc[mi][ni], 0, 0, 0);
      }

    LGKM0;
    asm volatile("s_waitcnt vmcnt(0)" ::: "memory");
    BARRIER;
  }

  // Epilogue: C/D layout col=lane&15, row=(lane>>4)*4+reg.
#pragma unroll
  for (int ni = 0; ni < 6; ++ni) {
    int c = col0 + wn * 96 + ni * 16 + (lane & 15);
    int which = c >> 10;
    int jj = c & (D_ - 1);
    int h = jj >> 6, dh = jj & 63;
    float bias = (c < D_) ? bq[c] : bkv[c - D_];
    float* dst = (which == 0) ? Qo : ((which == 1) ? Ko : Vo);
#pragma unroll
    for (int mi = 0; mi < 2; ++mi) {
#pragma unroll
      for (int reg = 0; reg < 4; ++reg) {
        int r = row0 + wm * 32 + mi * 16 + ((lane >> 4) << 2) + reg;
        int b = r >> 11, l = r & (L_ - 1);
        dst[(((size_t)b * H_ + h) * L_ + l) * DH_ + dh] =
            acc[mi][ni][reg] + bias;
      }
    }
    if (which == 2) {  // vmean partial: sum over this wave's 32 rows
      float s = 0.f;
#pragma unroll
      for (int mi = 0; mi < 2; ++mi)
#pragma unroll
        for (int reg = 0; reg < 4; ++reg) s += acc[mi][ni][reg];
      s += __shfl_xor(s, 16);
      s += __shfl_xor(s, 32);
      if ((lane >> 4) == 0)
        atomicAdd(&vmAcc[(row0 >> 11) * D_ + jj], s + 32.0f * bias);
    }
  }
#undef STG_ALL
}

// ---------------------------------------------------------------------------
// Fallback GEMM (R10 structure) — used only when ws can't hold Xhi/Xlo.
// ---------------------------------------------------------------------------
__global__ __launch_bounds__(256) void gemm_qkv_fallback(
    const float* __restrict__ X,
    const unsigned short* __restrict__ Whi,
    const unsigned short* __restrict__ Wlo,
    const float* __restrict__ bq, const float* __restrict__ bkv,
    float* __restrict__ Qo, float* __restrict__ Ko, float* __restrict__ Vo,
    float* __restrict__ vmAcc) {
  __shared__ unsigned short Ah[128 * 32];
  __shared__ unsigned short Al[128 * 32];
  __shared__ unsigned short Bh[128 * 32];
  __shared__ unsigned short Bl[128 * 32];
  const int tid = threadIdx.x;
  const int lane = tid & 63;
  const int wave = tid >> 6;
  const int wm = wave >> 1, wn = wave & 1;
  const int row0 = blockIdx.y * 128;
  const int col0 = blockIdx.x * 128;

  f32x4 acc[4][4] = {};

  const int grow = lane >> 2;
  const int gg = lane & 3;

  for (int k0 = 0; k0 < D_; k0 += 32) {
#pragma unroll
    for (int j = 0; j < 2; ++j) {
      int c = wave + 4 * j;
      int row = c * 16 + grow;
      int gsrc = (gg ^ ((row >> 1) & 3)) << 3;
      size_t soffB = (size_t)(col0 + row) * D_ + k0 + gsrc;
      gload16(Whi + soffB, Bh + c * 512);
      gload16(Wlo + soffB, Bl + c * 512);
    }
#pragma unroll
    for (int rep = 0; rep < 2; ++rep) {
      int task = tid + rep * 256;
      int row = task >> 2;
      int gt = task & 3;
      const float* s = X + (size_t)(row0 + row) * D_ + k0 + gt * 8;
      float4 a0 = *(const float4*)s;
      float4 a1 = *(const float4*)(s + 4);
      float av[8] = {a0.x, a0.y, a0.z, a0.w, a1.x, a1.y, a1.z, a1.w};
      short8v hseg, lseg;
#pragma unroll
      for (int e = 0; e < 8; ++e) {
        unsigned short hh = bf16_rne(av[e]);
        hseg[e] = (short)hh;
        lseg[e] = (short)bf16_rne(av[e] - bf16_f32(hh));
      }
      int dst = row * 32 + ((gt ^ ((row >> 1) & 3)) << 3);
      *(short8v*)&Ah[dst] = hseg;
      *(short8v*)&Al[dst] = lseg;
    }
    __syncthreads();

    short8v a_h[4], a_l[4], b_h[4], b_l[4];
    const int hs = lane >> 4;
#pragma unroll
    for (int mi = 0; mi < 4; ++mi) {
      int rr = wm * 64 + mi * 16 + (lane & 15);
      int off = rr * 32 + ((hs ^ ((rr >> 1) & 3)) << 3);
      a_h[mi] = *(const short8v*)&Ah[off];
      a_l[mi] = *(const short8v*)&Al[off];
    }
#pragma unroll
    for (int ni = 0; ni < 4; ++ni) {
      int rc = wn * 64 + ni * 16 + (lane & 15);
      int off = rc * 32 + ((hs ^ ((rc >> 1) & 3)) << 3);
      b_h[ni] = *(const short8v*)&Bh[off];
      b_l[ni] = *(const short8v*)&Bl[off];
    }
#pragma unroll
    for (int mi = 0; mi < 4; ++mi)
#pragma unroll
      for (int ni = 0; ni < 4; ++ni) {
        acc[mi][ni] = __builtin_amdgcn_mfma_f32_16x16x32_bf16(
            a_h[mi], b_h[ni], acc[mi][ni], 0, 0, 0);
        acc[mi][ni] = __builtin_amdgcn_mfma_f32_16x16x32_bf16(
            a_h[mi], b_l[ni], acc[mi][ni], 0, 0, 0);
        acc[mi][ni] = __builtin_amdgcn_mfma_f32_16x16x32_bf16(
            a_l[mi], b_h[ni], acc[mi][ni], 0, 0, 0);
      }
    __syncthreads();
  }

#pragma unroll
  for (int ni = 0; ni < 4; ++ni) {
    int c = col0 + wn * 64 + ni * 16 + (lane & 15);
    int which = c >> 10;
    int jj = c & (D_ - 1);
    int h = jj >> 6, dh = jj & 63;
    float bias = (c < D_) ? bq[c] : bkv[c - D_];
    float* dst = (which == 0) ? Qo : ((which == 1) ? Ko : Vo);
#pragma unroll
    for (int mi = 0; mi < 4; ++mi) {
#pragma unroll
      for (int reg = 0; reg < 4; ++reg) {
        int r = row0 + wm * 64 + mi * 16 + ((lane >> 4) << 2) + reg;
        int b = r >> 11, l = r & (L_ - 1);
        dst[(((size_t)b * H_ + h) * L_ + l) * DH_ + dh] =
            acc[mi][ni][reg] + bias;
      }
    }
    if (which == 2) {
      float s = 0.f;
#pragma unroll
      for (int mi = 0; mi < 4; ++mi)
#pragma unroll
        for (int reg = 0; reg < 4; ++reg) s += acc[mi][ni][reg];
      s += __shfl_xor(s, 16);
      s += __shfl_xor(s, 32);
      if ((lane >> 4) == 0)
        atomicAdd(&vmAcc[(row0 >> 11) * D_ + jj], s + 64.0f * bias);
    }
  }
}

// ---------------------------------------------------------------------------
// Merged kernel A: blocks [0,4096) = sample_m; blocks [4096,4128) = base.
// sample_m: bh = bid&31 -> all 128 blocks of one bh share an XCD.
// ---------------------------------------------------------------------------
__global__ __launch_bounds__(256) void sample_base(
    const float* __restrict__ Q, const float* __restrict__ Kt,
    const int* __restrict__ idx, float* __restrict__ Mv,
    const float* __restrict__ vmAcc, const float* __restrict__ Wout,
    const float* __restrict__ bout, float* __restrict__ baseOut,
    float* __restrict__ vmeanM) {
  int t = threadIdx.x;
  if (blockIdx.x < 4096) {
    int bh = blockIdx.x & 31;
    int chunk = blockIdx.x >> 5;
    int w = t >> 6, lane = t & 63;
    int subl = lane >> 4, d16 = lane & 15;
    int l = chunk * 16 + w * 4 + subl;
    int gl = bh * L_ + l;
    const float4* Kb4 = (const float4*)(Kt + (size_t)bh * L_ * DH_);
    float4 q4 = ((const float4*)(Q + (size_t)gl * DH_))[d16];
    const int* irow = idx + l * U_;
    float mx = -INFINITY, sm = 0.f;
#pragma unroll 8
    for (int u = 0; u < U_; ++u) {
      int kl = irow[u];
      float4 k4 = Kb4[kl * 16 + d16];
      float p = q4.x * k4.x + q4.y * k4.y + q4.z * k4.z + q4.w * k4.w;
      p += __shfl_xor(p, 1);
      p += __shfl_xor(p, 2);
      p += __shfl_xor(p, 4);
      p += __shfl_xor(p, 8);
      mx = fmaxf(mx, p);
      sm += p;
    }
    if (d16 == 0) Mv[gl] = mx - sm * (1.0f / U_);
  } else {
    int bid = blockIdx.x - 4096;
    int b = bid >> 4, jc = bid & 15;
    int j = jc * 64 + (t & 63);
    int isl = t >> 6;
    __shared__ float vm[D_];
    __shared__ float red[256];
    for (int i = t; i < D_; i += 256) vm[i] = vmAcc[b * D_ + i] * (1.0f / L_);
    __syncthreads();
    if (jc == 0)
      for (int i = t; i < D_; i += 256) vmeanM[b * D_ + i] = vm[i];
    float s = 0.f;
    const float* wr = Wout + (size_t)j * D_ + isl * 256;
    const float* vv = vm + isl * 256;
    for (int i = 0; i < 256; i += 4) {
      float4 w = *(const float4*)(wr + i);
      s += vv[i] * w.x + vv[i + 1] * w.y + vv[i + 2] * w.z + vv[i + 3] * w.w;
    }
    red[t] = s;
    __syncthreads();
    if (isl == 0)
      baseOut[b * D_ + j] =
          red[t] + red[t + 64] + red[t + 128] + red[t + 192] + bout[j];
  }
}

// ---------------------------------------------------------------------------
// Merged kernel B: blocks [0,4096) = bcast_out; [4096,4128) = topk.
// ---------------------------------------------------------------------------
__global__ __launch_bounds__(256) void bcast_topk(
    const float* __restrict__ baseIn, float* __restrict__ out,
    const float* __restrict__ Mv, int* __restrict__ topIdx) {
  int t = threadIdx.x;
  if (blockIdx.x < 4096) {
    size_t i4 = (size_t)blockIdx.x * 256 + t;
    size_t i = i4 * 4;
    int b = (int)(i >> 21);
    int col = (int)(i & (D_ - 1));
    *(float4*)(out + i) = *(const float4*)(baseIn + b * D_ + col);
  } else {
    __shared__ float vals[L_];
    int lane = t & 63;
    int bh = blockIdx.x - 4096;
    for (int j = t; j < L_; j += 256) vals[j] = Mv[(size_t)bh * L_ + j];
    __syncthreads();
    for (int it = 0; it < U_; ++it) {
      float bv = -INFINITY;
      int bi = 0x7fffffff;
      for (int j = 0; j < 32; ++j) {
        int i = j * 64 + lane;
        float v = vals[i];
        if (v > bv) { bv = v; bi = i; }
      }
#pragma unroll
      for (int off = 32; off > 0; off >>= 1) {
        float ov = __shfl_xor(bv, off);
        int oi = __shfl_xor(bi, off);
        if (ov > bv || (ov == bv && oi < bi)) { bv = ov; bi = oi; }
      }
      if (t == 0) topIdx[bh * U_ + it] = bi;
      vals[bi] = -INFINITY;  // all waves compute identical bi
      __syncthreads();
    }
  }
}

// ---------------------------------------------------------------------------
// Fused attention + output correction (R18 version, exact). Grid (32, 8):
// blockIdx.x = bh so the 8 qc-blocks of one bh share an XCD.
// ---------------------------------------------------------------------------
__global__ __launch_bounds__(256) void attn_corr(
    const float* __restrict__ Q, const float* __restrict__ Kt,
    const float* __restrict__ Vt, const int* __restrict__ topIdx,
    const float* __restrict__ vmeanM, const float* __restrict__ Wout,
    float* __restrict__ out) {
  int bh = blockIdx.x;  // 0..31
  int qc = blockIdx.y;  // 0..7 (5 queries each)
  int b = bh >> 4, h = bh & (H_ - 1);
  __shared__ float Qs[5][DH_];
  __shared__ float Sv[5][L_];
  __shared__ float part[4][5][DH_];
  __shared__ float inv[5];
  __shared__ float dv[5][DH_];
  __shared__ int lq[5];
  int t = threadIdx.x;
  int lane = t & 63, w = t >> 6;

  if (t < 80) {
    int q = t >> 4, c4 = t & 15;
    int ql = topIdx[bh * U_ + qc * 5 + q];
    *(float4*)&Qs[q][c4 * 4] =
        *(const float4*)&Q[((size_t)bh * L_ + ql) * DH_ + c4 * 4];
  }
  if (t < 5) lq[t] = topIdx[bh * U_ + qc * 5 + t];
  __syncthreads();

  const float* Kb = Kt + (size_t)bh * L_ * DH_;
  for (int kc = 0; kc < 8; ++kc) {
    int key = kc * 256 + t;
    const float* kr = Kb + (size_t)key * DH_;
    float acc[5];
#pragma unroll
    for (int q = 0; q < 5; ++q) acc[q] = 0.f;
#pragma unroll
    for (int i4 = 0; i4 < 16; ++i4) {
      float4 k4 = *(const float4*)(kr + i4 * 4);
#pragma unroll
      for (int q = 0; q < 5; ++q) {
        float4 qv = *(const float4*)&Qs[q][i4 * 4];
        acc[q] += k4.x * qv.x + k4.y * qv.y + k4.z * qv.z + k4.w * qv.w;
      }
    }
#pragma unroll
    for (int q = 0; q < 5; ++q) Sv[q][key] = acc[q] * SCALE_;
  }
  __syncthreads();

#pragma unroll
  for (int rep = 0; rep < 2; ++rep) {
    int r = (rep == 0) ? w : (w == 0 ? 4 : -1);
    if (r >= 0) {
      float mx = -INFINITY;
      for (int j = 0; j < 32; ++j) mx = fmaxf(mx, Sv[r][j * 64 + lane]);
#pragma unroll
      for (int off = 1; off < 64; off <<= 1)
        mx = fmaxf(mx, __shfl_xor(mx, off));
      float sm = 0.f;
      for (int j = 0; j < 32; ++j) {
        float e = __expf(Sv[r][j * 64 + lane] - mx);
        Sv[r][j * 64 + lane] = e;
        sm += e;
      }
#pragma unroll
      for (int off = 1; off < 64; off <<= 1) sm += __shfl_xor(sm, off);
      if (lane == 0) inv[r] = 1.0f / sm;
    }
  }
  __syncthreads();

  {
    const float* vb = Vt + ((size_t)bh * L_ + w * 512) * DH_ + lane;
    float acc[5];
#pragma unroll
    for (int q = 0; q < 5; ++q) acc[q] = 0.f;
    for (int k4 = 0; k4 < 128; ++k4) {
      float v0 = vb[(k4 * 4 + 0) * DH_];
      float v1 = vb[(k4 * 4 + 1) * DH_];
      float v2 = vb[(k4 * 4 + 2) * DH_];
      float v3 = vb[(k4 * 4 + 3) * DH_];
      int k = w * 512 + k4 * 4;
#pragma unroll
      for (int q = 0; q < 5; ++q) {
        float4 p4 = *(const float4*)&Sv[q][k];
        acc[q] += p4.x * v0 + p4.y * v1 + p4.z * v2 + p4.w * v3;
      }
    }
#pragma unroll
    for (int q = 0; q < 5; ++q) part[w][q][lane] = acc[q];
  }
  __syncthreads();

  for (int o = t; o < 5 * DH_; o += 256) {
    int q = o >> 6, dh = o & 63;
    float s = (part[0][q][dh] + part[1][q][dh]) +
              (part[2][q][dh] + part[3][q][dh]);
    dv[q][dh] = s * inv[q] - vmeanM[b * D_ + h * DH_ + dh];
  }
  __syncthreads();

  int sub = t & 3;
  int jbase = t >> 2;
#pragma unroll
  for (int jc = 0; jc < 16; ++jc) {
    int j = jc * 64 + jbase;
    const float* wr = Wout + (size_t)j * D_ + h * DH_ + sub * 16;
    float4 w0 = ((const float4*)wr)[0];
    float4 w1 = ((const float4*)wr)[1];
    float4 w2 = ((const float4*)wr)[2];
    float4 w3 = ((const float4*)wr)[3];
#pragma unroll
    for (int q = 0; q < 5; ++q) {
      const float* dq = &dv[q][sub * 16];
      float s = dq[0] * w0.x + dq[1] * w0.y + dq[2] * w0.z + dq[3] * w0.w +
                dq[4] * w1.x + dq[5] * w1.y + dq[6] * w1.z + dq[7] * w1.w +
                dq[8] * w2.x + dq[9] * w2.y + dq[10] * w2.z + dq[11] * w2.w +
                dq[12] * w3.x + dq[13] * w3.y + dq[14] * w3.z + dq[15] * w3.w;
      s += __shfl_xor(s, 1);
      s += __shfl_xor(s, 2);
      if (sub == 0)
        atomicAdd(out + ((size_t)b * L_ + lq[q]) * D_ + j, s);
    }
  }
}

// ---------------------------------------------------------------------------
extern "C" void kernel_launch(void* const* d_in, const int* in_sizes, int n_in,
                              void* d_out, int out_size, void* d_ws,
                              size_t ws_size, hipStream_t stream) {
  const float* x    = (const float*)d_in[0];
  const float* Wq   = (const float*)d_in[1];
  const float* bq   = (const float*)d_in[2];
  const float* Wkv  = (const float*)d_in[3];
  const float* bkv  = (const float*)d_in[4];
  const float* Wout = (const float*)d_in[5];
  const float* bout = (const float*)d_in[6];
  const int*   idx  = (const int*)d_in[7];
  float* out = (float*)d_out;

  float* ws = (float*)d_ws;
  const size_t NQ = (size_t)B_ * H_ * L_ * DH_;  // 4,194,304 floats
  float* Q  = ws;
  float* Kt = Q + NQ;
  float* Vt = Kt + NQ;
  // W/X split region (live only through the GEMM)
  unsigned short* Whi = (unsigned short*)(Vt + NQ);  // 6 MB
  unsigned short* Wlo = Whi + (size_t)3 * D_ * D_;   // 6 MB
  unsigned short* Xhi = Wlo + (size_t)3 * D_ * D_;   // 8 MB (optional)
  unsigned short* Xlo = Xhi + NQ;                    // 8 MB (optional)
  // phase-2 region (overlaps split region; used only after the GEMM)
  float* Mv     = Vt + NQ;                           // 256 KB
  float* vmeanM = Mv + (size_t)B_ * H_ * L_;         // 8 KB
  float* baseB  = vmeanM + B_ * D_;                  // 8 KB
  int*   topIdx = (int*)(baseB + B_ * D_);           // 5 KB
  // vmean accumulator lives in d_out[0:2048].
  float* vmAcc = out;

  const bool xsplit = ws_size >= ((size_t)76 << 20);
  const int nW = 3 * D_ * D_ / 4;
  const int nX = (int)(NQ / 4);

  if (xsplit) {
    split_all<<<dim3((nW + nX) / 256), dim3(256), 0, stream>>>(
        Wq, Wkv, x, Whi, Wlo, Xhi, Xlo, vmAcc, nW);
    gemm_qkv_16w<<<dim3(3 * D_ / 384, B_ * L_ / 128), dim3(1024), 0,
                   stream>>>(Xhi, Xlo, Whi, Wlo, bq, bkv, Q, Kt, Vt, vmAcc);
  } else {
    split_all<<<dim3(nW / 256), dim3(256), 0, stream>>>(Wq, Wkv, x, Whi, Wlo,
                                                        Xhi, Xlo, vmAcc, nW);
    gemm_qkv_fallback<<<dim3(3 * D_ / 128, B_ * L_ / 128), dim3(256), 0,
                        stream>>>(x, Whi, Wlo, bq, bkv, Q, Kt, Vt, vmAcc);
  }
  sample_base<<<dim3(4096 + B_ * 16), dim3(256), 0, stream>>>(
      Q, Kt, idx, Mv, vmAcc, Wout, bout, baseB, vmeanM);
  bcast_topk<<<dim3(4096 + B_ * H_), dim3(256), 0, stream>>>(baseB, out, Mv,
                                                             topIdx);
  attn_corr<<<dim3(32, 8), dim3(256), 0, stream>>>(Q, Kt, Vt, topIdx, vmeanM,
                                                   Wout, out);
}